// Round 2
// baseline (671.538 us; speedup 1.0000x reference)
//
#include <hip/hip_runtime.h>

#define NN 100000
#define EE 1600000
#define ETOT (EE + NN)          // 1,700,000 edges incl. self-loops
#define IND 32
#define HIDD 64
#define NHEADS 4
#define HOD 16
#define OUTD 32
#define HID2D 32
#define NBLK 391                // ceil(NN/256)

// ---------- linear 1: h1 = x @ W1 ; as1/ad1 = per-head attention dots ----------
__global__ __launch_bounds__(256) void k_lin1(
    const float* __restrict__ x, const float* __restrict__ W1,
    const float* __restrict__ atsrc, const float* __restrict__ atdst,
    float* __restrict__ h1, float* __restrict__ as1, float* __restrict__ ad1) {
  __shared__ float Ws[IND * HIDD];
  __shared__ float xs[4 * IND];
  __shared__ float atS[HIDD], atD[HIDD];
  int t = threadIdx.x;
  for (int i = t; i < IND * HIDD; i += 256) Ws[i] = W1[i];
  if (t < HIDD) { atS[t] = atsrc[t]; atD[t] = atdst[t]; }
  if (t < 128) xs[t] = x[blockIdx.x * 128 + t];
  __syncthreads();
  int nl = t >> 6, j = t & 63;
  int node = blockIdx.x * 4 + nl;
  float acc = 0.f;
#pragma unroll
  for (int k = 0; k < IND; k++) acc += xs[nl * IND + k] * Ws[k * HIDD + j];
  h1[node * HIDD + j] = acc;
  float ps = acc * atS[j], pd = acc * atD[j];
#pragma unroll
  for (int off = 8; off >= 1; off >>= 1) {
    ps += __shfl_down(ps, off, 16);
    pd += __shfl_down(pd, off, 16);
  }
  if ((j & 15) == 0) {
    as1[node * NHEADS + (j >> 4)] = ps;
    ad1[node * NHEADS + (j >> 4)] = pd;
  }
}

// ---------- linear 2: h2 = hbn @ W2 ; as2/ad2 ----------
__global__ __launch_bounds__(256) void k_lin2(
    const float* __restrict__ hbn, const float* __restrict__ W2,
    const float* __restrict__ atsrc, const float* __restrict__ atdst,
    float* __restrict__ h2, float* __restrict__ as2, float* __restrict__ ad2) {
  __shared__ float Ws[HIDD * OUTD];
  __shared__ float xs[8 * HIDD];
  __shared__ float atS[OUTD], atD[OUTD];
  int t = threadIdx.x;
  for (int i = t; i < HIDD * OUTD; i += 256) Ws[i] = W2[i];
  if (t < OUTD) { atS[t] = atsrc[t]; atD[t] = atdst[t]; }
  for (int i = t; i < 8 * HIDD; i += 256) xs[i] = hbn[blockIdx.x * 8 * HIDD + i];
  __syncthreads();
  int nl = t >> 5, j = t & 31;
  int node = blockIdx.x * 8 + nl;
  float acc = 0.f;
#pragma unroll
  for (int k = 0; k < HIDD; k++) acc += xs[nl * HIDD + k] * Ws[k * OUTD + j];
  h2[node * OUTD + j] = acc;
  float ps = acc * atS[j], pd = acc * atD[j];
#pragma unroll
  for (int off = 16; off >= 1; off >>= 1) {
    ps += __shfl_down(ps, off, 32);
    pd += __shfl_down(pd, off, 32);
  }
  if (j == 0) { as2[node] = ps; ad2[node] = pd; }
}

// ---------- CSR build ----------
__global__ void k_hist(const int* __restrict__ ei, int* __restrict__ deg) {
  int i = blockIdx.x * 256 + threadIdx.x;
  if (i >= ETOT) return;
  int d = (i < EE) ? ei[EE + i] : (i - EE);
  atomicAdd(&deg[d], 1);
}

__global__ __launch_bounds__(256) void k_scan1(const int* __restrict__ deg,
                                               int* __restrict__ rowp,
                                               int* __restrict__ bsum) {
  __shared__ int sm[256];
  int t = threadIdx.x;
  int i = blockIdx.x * 256 + t;
  int v = (i < NN) ? deg[i] : 0;
  sm[t] = v;
  __syncthreads();
  for (int off = 1; off < 256; off <<= 1) {
    int xv = (t >= off) ? sm[t - off] : 0;
    __syncthreads();
    sm[t] += xv;
    __syncthreads();
  }
  if (i < NN) rowp[i] = sm[t] - v;   // exclusive within block
  if (t == 255) bsum[blockIdx.x] = sm[255];
}

__global__ __launch_bounds__(512) void k_scan2(int* __restrict__ bsum) {
  __shared__ int sm[512];
  int t = threadIdx.x;
  int v = (t < NBLK) ? bsum[t] : 0;
  sm[t] = v;
  __syncthreads();
  for (int off = 1; off < 512; off <<= 1) {
    int xv = (t >= off) ? sm[t - off] : 0;
    __syncthreads();
    sm[t] += xv;
    __syncthreads();
  }
  bsum[t] = sm[t] - v;               // exclusive block offsets
}

__global__ __launch_bounds__(256) void k_scan3(int* __restrict__ rowp,
                                               const int* __restrict__ bsum,
                                               int* __restrict__ cur) {
  int i = blockIdx.x * 256 + threadIdx.x;
  if (i < NN) {
    int r = rowp[i] + bsum[blockIdx.x];
    rowp[i] = r;
    cur[i] = r;
  } else if (i == NN) {
    rowp[NN] = ETOT;
  }
}

__global__ void k_scatter(const int* __restrict__ ei, int* __restrict__ cur,
                          int* __restrict__ srcs) {
  int i = blockIdx.x * 256 + threadIdx.x;
  if (i >= ETOT) return;
  int s, d;
  if (i < EE) { s = ei[i]; d = ei[EE + i]; } else { s = i - EE; d = s; }
  int pos = atomicAdd(&cur[d], 1);
  srcs[pos] = s;
}

// ---------- GAT1 aggregation + bias + BN1 + ReLU (wave per node) ----------
__global__ __launch_bounds__(256) void k_agg1(
    const int* __restrict__ rowp, const int* __restrict__ srcs,
    const float* __restrict__ h1, const float* __restrict__ as1,
    const float* __restrict__ ad1, const float* __restrict__ b1,
    const float* __restrict__ g, const float* __restrict__ bb,
    const float* __restrict__ m, const float* __restrict__ v,
    float* __restrict__ hbn) {
  int t = threadIdx.x;
  int wid = t >> 6, lane = t & 63;
  int node = blockIdx.x * 4 + wid;
  int hd = lane >> 4;
  int start = rowp[node], end = rowp[node + 1];
  float adv = ad1[node * NHEADS + hd];
  float acc = 0.f, l = 0.f;
  for (int p = start; p < end; p++) {
    int s = srcs[p];
    float e = as1[s * NHEADS + hd] + adv;
    e = e > 0.f ? e : 0.2f * e;
    float ex = __expf(e);
    l += ex;
    acc += ex * h1[s * HIDD + lane];
  }
  float o = acc / (l + 1e-16f) + b1[lane];
  float bn = (o - m[lane]) * rsqrtf(v[lane] + 1e-5f) * g[lane] + bb[lane];
  hbn[node * HIDD + lane] = fmaxf(bn, 0.f);
}

// ---------- GAT2 aggregation + bias + BN2 + ReLU (32-lane group per node) ----------
__global__ __launch_bounds__(256) void k_agg2(
    const int* __restrict__ rowp, const int* __restrict__ srcs,
    const float* __restrict__ h2, const float* __restrict__ as2,
    const float* __restrict__ ad2, const float* __restrict__ b2v,
    const float* __restrict__ g, const float* __restrict__ bb,
    const float* __restrict__ m, const float* __restrict__ v,
    float* __restrict__ out_emb) {
  int t = threadIdx.x;
  int grp = t >> 5, lane = t & 31;
  int node = blockIdx.x * 8 + grp;
  int start = rowp[node], end = rowp[node + 1];
  float adv = ad2[node];
  float acc = 0.f, l = 0.f;
  for (int p = start; p < end; p++) {
    int s = srcs[p];
    float e = as2[s] + adv;
    e = e > 0.f ? e : 0.2f * e;
    float ex = __expf(e);
    l += ex;
    acc += ex * h2[s * OUTD + lane];
  }
  float o = acc / (l + 1e-16f) + b2v[lane];
  float bn = (o - m[lane]) * rsqrtf(v[lane] + 1e-5f) * g[lane] + bb[lane];
  out_emb[node * OUTD + lane] = fmaxf(bn, 0.f);
}

// ---------- classifier + regressor heads (thread per node) ----------
__global__ __launch_bounds__(256) void k_mlp(
    const float* __restrict__ embf,
    const float* __restrict__ cw1, const float* __restrict__ cb1,
    const float* __restrict__ cw2, const float* __restrict__ cb2,
    const float* __restrict__ rw1, const float* __restrict__ rb1,
    const float* __restrict__ rw2, const float* __restrict__ rb2,
    float* __restrict__ out_roles, float* __restrict__ out_energy) {
  __shared__ float C1[OUTD * HID2D], R1[OUTD * HID2D];
  __shared__ float C2[HID2D * 3], CB1[HID2D], RB1[HID2D], R2[HID2D];
  __shared__ float CB2v[3], RB2v;
  int t = threadIdx.x;
  for (int i = t; i < OUTD * HID2D; i += 256) { C1[i] = cw1[i]; R1[i] = rw1[i]; }
  if (t < HID2D) { CB1[t] = cb1[t]; RB1[t] = rb1[t]; R2[t] = rw2[t]; }
  if (t < HID2D * 3) C2[t] = cw2[t];
  if (t < 3) CB2v[t] = cb2[t];
  if (t == 0) RB2v = rb2[0];
  __syncthreads();
  int node = blockIdx.x * 256 + t;
  if (node >= NN) return;
  float e[OUTD];
#pragma unroll
  for (int k = 0; k < OUTD; k++) e[k] = embf[node * OUTD + k];
  float r0 = CB2v[0], r1 = CB2v[1], r2 = CB2v[2], en = RB2v;
  for (int j = 0; j < HID2D; j++) {
    float hc = CB1[j], hr = RB1[j];
#pragma unroll
    for (int k = 0; k < OUTD; k++) {
      hc += e[k] * C1[k * HID2D + j];
      hr += e[k] * R1[k * HID2D + j];
    }
    hc = fmaxf(hc, 0.f);
    hr = fmaxf(hr, 0.f);
    r0 += hc * C2[j * 3 + 0];
    r1 += hc * C2[j * 3 + 1];
    r2 += hc * C2[j * 3 + 2];
    en += hr * R2[j];
  }
  out_roles[node * 3 + 0] = r0;
  out_roles[node * 3 + 1] = r1;
  out_roles[node * 3 + 2] = r2;
  out_energy[node] = en;
}

extern "C" void kernel_launch(void* const* d_in, const int* in_sizes, int n_in,
                              void* d_out, int out_size, void* d_ws, size_t ws_size,
                              hipStream_t stream) {
  const float* x    = (const float*)d_in[0];
  const int*   ei   = (const int*)d_in[1];
  const float* W1   = (const float*)d_in[2];
  const float* as1w = (const float*)d_in[3];
  const float* ad1w = (const float*)d_in[4];
  const float* b1   = (const float*)d_in[5];
  const float* W2   = (const float*)d_in[6];
  const float* as2w = (const float*)d_in[7];
  const float* ad2w = (const float*)d_in[8];
  const float* b2v  = (const float*)d_in[9];
  const float* bn1g = (const float*)d_in[10];
  const float* bn1b = (const float*)d_in[11];
  const float* bn1m = (const float*)d_in[12];
  const float* bn1v = (const float*)d_in[13];
  const float* bn2g = (const float*)d_in[14];
  const float* bn2b = (const float*)d_in[15];
  const float* bn2m = (const float*)d_in[16];
  const float* bn2v = (const float*)d_in[17];
  const float* cw1  = (const float*)d_in[18];
  const float* cb1  = (const float*)d_in[19];
  const float* cw2  = (const float*)d_in[20];
  const float* cb2  = (const float*)d_in[21];
  const float* rw1  = (const float*)d_in[22];
  const float* rb1  = (const float*)d_in[23];
  const float* rw2  = (const float*)d_in[24];
  const float* rb2  = (const float*)d_in[25];

  // workspace layout (~62 MB)
  float* ws  = (float*)d_ws;
  float* h1  = ws;                        // N*64
  float* hbn = h1 + NN * HIDD;            // N*64
  float* as1 = hbn + NN * HIDD;           // N*4
  float* ad1 = as1 + NN * NHEADS;         // N*4
  int* deg   = (int*)(ad1 + NN * NHEADS); // N
  int* rowp  = deg + NN;                  // N+1
  int* cur   = rowp + NN + 1;             // N
  int* bsum  = cur + NN;                  // 1024
  int* srcs  = bsum + 1024;               // ETOT
  float* h2   = h1;                       // N*32 fits in h1's slot
  float* as2  = as1;
  float* ad2  = ad1;

  float* out        = (float*)d_out;
  float* out_emb    = out;                   // N*32
  float* out_roles  = out + NN * OUTD;       // N*3
  float* out_energy = out + NN * (OUTD + 3); // N*1

  hipMemsetAsync(deg, 0, NN * sizeof(int), stream);
  k_lin1<<<NN / 4, 256, 0, stream>>>(x, W1, as1w, ad1w, h1, as1, ad1);
  k_hist<<<(ETOT + 255) / 256, 256, 0, stream>>>(ei, deg);
  k_scan1<<<NBLK, 256, 0, stream>>>(deg, rowp, bsum);
  k_scan2<<<1, 512, 0, stream>>>(bsum);
  k_scan3<<<NBLK, 256, 0, stream>>>(rowp, bsum, cur);
  k_scatter<<<(ETOT + 255) / 256, 256, 0, stream>>>(ei, cur, srcs);
  k_agg1<<<NN / 4, 256, 0, stream>>>(rowp, srcs, h1, as1, ad1, b1, bn1g, bn1b, bn1m, bn1v, hbn);
  k_lin2<<<NN / 8, 256, 0, stream>>>(hbn, W2, as2w, ad2w, h2, as2, ad2);
  k_agg2<<<NN / 8, 256, 0, stream>>>(rowp, srcs, h2, as2, ad2, b2v, bn2g, bn2b, bn2m, bn2v, out_emb);
  k_mlp<<<(NN + 255) / 256, 256, 0, stream>>>(out_emb, cw1, cb1, cw2, cb2, rw1, rb1, rw2, rb2, out_roles, out_energy);
}

// Round 3
// 534.023 us; speedup vs baseline: 1.2575x; 1.2575x over previous
//
#include <hip/hip_runtime.h>

#define NN 100000
#define EE 1600000
#define ETOT (EE + NN)          // 1,700,000 edges incl. self-loops
#define IND 32
#define HIDD 64
#define NHEADS 4
#define HOD 16
#define OUTD 32
#define HID2D 32
#define NBLK 391                // ceil(NN/256)

// ---------- linear 1: h1 = x @ W1 ; as1/ad1 = per-head attention dots ----------
__global__ __launch_bounds__(256) void k_lin1(
    const float* __restrict__ x, const float* __restrict__ W1,
    const float* __restrict__ atsrc, const float* __restrict__ atdst,
    float* __restrict__ h1, float* __restrict__ as1, float* __restrict__ ad1) {
  __shared__ float Ws[IND * HIDD];
  __shared__ float xs[4 * IND];
  __shared__ float atS[HIDD], atD[HIDD];
  int t = threadIdx.x;
  for (int i = t; i < IND * HIDD; i += 256) Ws[i] = W1[i];
  if (t < HIDD) { atS[t] = atsrc[t]; atD[t] = atdst[t]; }
  if (t < 128) xs[t] = x[blockIdx.x * 128 + t];
  __syncthreads();
  int nl = t >> 6, j = t & 63;
  int node = blockIdx.x * 4 + nl;
  float acc = 0.f;
#pragma unroll
  for (int k = 0; k < IND; k++) acc += xs[nl * IND + k] * Ws[k * HIDD + j];
  h1[node * HIDD + j] = acc;
  float ps = acc * atS[j], pd = acc * atD[j];
#pragma unroll
  for (int off = 8; off >= 1; off >>= 1) {
    ps += __shfl_down(ps, off, 16);
    pd += __shfl_down(pd, off, 16);
  }
  if ((j & 15) == 0) {
    as1[node * NHEADS + (j >> 4)] = ps;
    ad1[node * NHEADS + (j >> 4)] = pd;
  }
}

// ---------- linear 2: h2 = hbn @ W2 ; as2/ad2 ----------
__global__ __launch_bounds__(256) void k_lin2(
    const float* __restrict__ hbn, const float* __restrict__ W2,
    const float* __restrict__ atsrc, const float* __restrict__ atdst,
    float* __restrict__ h2, float* __restrict__ as2, float* __restrict__ ad2) {
  __shared__ float Ws[HIDD * OUTD];
  __shared__ float xs[8 * HIDD];
  __shared__ float atS[OUTD], atD[OUTD];
  int t = threadIdx.x;
  for (int i = t; i < HIDD * OUTD; i += 256) Ws[i] = W2[i];
  if (t < OUTD) { atS[t] = atsrc[t]; atD[t] = atdst[t]; }
  for (int i = t; i < 8 * HIDD; i += 256) xs[i] = hbn[blockIdx.x * 8 * HIDD + i];
  __syncthreads();
  int nl = t >> 5, j = t & 31;
  int node = blockIdx.x * 8 + nl;
  float acc = 0.f;
#pragma unroll
  for (int k = 0; k < HIDD; k++) acc += xs[nl * HIDD + k] * Ws[k * OUTD + j];
  h2[node * OUTD + j] = acc;
  float ps = acc * atS[j], pd = acc * atD[j];
#pragma unroll
  for (int off = 16; off >= 1; off >>= 1) {
    ps += __shfl_down(ps, off, 32);
    pd += __shfl_down(pd, off, 32);
  }
  if (j == 0) { as2[node] = ps; ad2[node] = pd; }
}

// ---------- CSR build ----------
__global__ void k_hist(const int* __restrict__ ei, int* __restrict__ deg) {
  int i = blockIdx.x * 256 + threadIdx.x;
  if (i >= ETOT) return;
  int d = (i < EE) ? ei[EE + i] : (i - EE);
  atomicAdd(&deg[d], 1);
}

__global__ __launch_bounds__(256) void k_scan1(const int* __restrict__ deg,
                                               int* __restrict__ rowp,
                                               int* __restrict__ bsum) {
  __shared__ int sm[256];
  int t = threadIdx.x;
  int i = blockIdx.x * 256 + t;
  int v = (i < NN) ? deg[i] : 0;
  sm[t] = v;
  __syncthreads();
  for (int off = 1; off < 256; off <<= 1) {
    int xv = (t >= off) ? sm[t - off] : 0;
    __syncthreads();
    sm[t] += xv;
    __syncthreads();
  }
  if (i < NN) rowp[i] = sm[t] - v;   // exclusive within block
  if (t == 255) bsum[blockIdx.x] = sm[255];
}

__global__ __launch_bounds__(512) void k_scan2(int* __restrict__ bsum) {
  __shared__ int sm[512];
  int t = threadIdx.x;
  int v = (t < NBLK) ? bsum[t] : 0;
  sm[t] = v;
  __syncthreads();
  for (int off = 1; off < 512; off <<= 1) {
    int xv = (t >= off) ? sm[t - off] : 0;
    __syncthreads();
    sm[t] += xv;
    __syncthreads();
  }
  bsum[t] = sm[t] - v;               // exclusive block offsets
}

__global__ __launch_bounds__(256) void k_scan3(int* __restrict__ rowp,
                                               const int* __restrict__ bsum,
                                               int* __restrict__ cur) {
  int i = blockIdx.x * 256 + threadIdx.x;
  if (i < NN) {
    int r = rowp[i] + bsum[blockIdx.x];
    rowp[i] = r;
    cur[i] = r;
  } else if (i == NN) {
    rowp[NN] = ETOT;
  }
}

__global__ void k_scatter(const int* __restrict__ ei, int* __restrict__ cur,
                          int* __restrict__ srcs) {
  int i = blockIdx.x * 256 + threadIdx.x;
  if (i >= ETOT) return;
  int s, d;
  if (i < EE) { s = ei[i]; d = ei[EE + i]; } else { s = i - EE; d = s; }
  int pos = atomicAdd(&cur[d], 1);
  srcs[pos] = s;
}

// ---------- GAT1 aggregation + bias + BN1 + ReLU ----------
// wave per node; 4 quarters x 16 lanes; each quarter handles one edge,
// each lane holds float4 of features (fl*4..fl*4+3, head = fl>>2).
__global__ __launch_bounds__(256) void k_agg1(
    const int* __restrict__ rowp, const int* __restrict__ srcs,
    const float* __restrict__ h1, const float* __restrict__ as1,
    const float* __restrict__ ad1, const float* __restrict__ b1,
    const float* __restrict__ g, const float* __restrict__ bb,
    const float* __restrict__ m, const float* __restrict__ v,
    float* __restrict__ hbn) {
  int t = threadIdx.x;
  int wid = t >> 6, lane = t & 63;
  int node = blockIdx.x * 4 + wid;
  int q = lane >> 4;         // edge slot within chunk of 4
  int fl = lane & 15;        // feature group: floats fl*4..fl*4+3
  int hd = fl >> 2;          // head of this feature group
  int start = rowp[node], end = rowp[node + 1];
  float adv = ad1[node * NHEADS + hd];
  float4 acc = {0.f, 0.f, 0.f, 0.f};
  float l = 0.f;
  for (int p = start + q; p < end; p += 4) {
    int s = srcs[p];
    float e = as1[s * NHEADS + hd] + adv;
    e = e > 0.f ? e : 0.2f * e;
    float ex = __expf(e);
    l += ex;
    float4 hv = *(const float4*)(h1 + s * HIDD + fl * 4);
    acc.x += ex * hv.x; acc.y += ex * hv.y;
    acc.z += ex * hv.z; acc.w += ex * hv.w;
  }
  // combine the 4 quarters (lane bits 4,5)
#pragma unroll
  for (int off = 16; off <= 32; off <<= 1) {
    acc.x += __shfl_xor(acc.x, off, 64);
    acc.y += __shfl_xor(acc.y, off, 64);
    acc.z += __shfl_xor(acc.z, off, 64);
    acc.w += __shfl_xor(acc.w, off, 64);
    l     += __shfl_xor(l,     off, 64);
  }
  if (q == 0) {
    float li = 1.f / (l + 1e-16f);
    float4 bv = *(const float4*)(b1 + fl * 4);
    float4 mv = *(const float4*)(m + fl * 4);
    float4 vv = *(const float4*)(v + fl * 4);
    float4 gv = *(const float4*)(g + fl * 4);
    float4 bbv = *(const float4*)(bb + fl * 4);
    float4 o;
    o.x = fmaxf((acc.x * li + bv.x - mv.x) * rsqrtf(vv.x + 1e-5f) * gv.x + bbv.x, 0.f);
    o.y = fmaxf((acc.y * li + bv.y - mv.y) * rsqrtf(vv.y + 1e-5f) * gv.y + bbv.y, 0.f);
    o.z = fmaxf((acc.z * li + bv.z - mv.z) * rsqrtf(vv.z + 1e-5f) * gv.z + bbv.z, 0.f);
    o.w = fmaxf((acc.w * li + bv.w - mv.w) * rsqrtf(vv.w + 1e-5f) * gv.w + bbv.w, 0.f);
    *(float4*)(hbn + node * HIDD + fl * 4) = o;
  }
}

// ---------- GAT2 aggregation + bias + BN2 + ReLU ----------
// wave per node; 8 octants x 8 lanes; each octant one edge; lane float4.
__global__ __launch_bounds__(256) void k_agg2(
    const int* __restrict__ rowp, const int* __restrict__ srcs,
    const float* __restrict__ h2, const float* __restrict__ as2,
    const float* __restrict__ ad2, const float* __restrict__ b2v,
    const float* __restrict__ g, const float* __restrict__ bb,
    const float* __restrict__ m, const float* __restrict__ v,
    float* __restrict__ out_emb) {
  int t = threadIdx.x;
  int wid = t >> 6, lane = t & 63;
  int node = blockIdx.x * 4 + wid;
  int oc = lane >> 3;        // edge slot within chunk of 8
  int fl = lane & 7;         // feature group: floats fl*4..fl*4+3
  int start = rowp[node], end = rowp[node + 1];
  float adv = ad2[node];
  float4 acc = {0.f, 0.f, 0.f, 0.f};
  float l = 0.f;
  for (int p = start + oc; p < end; p += 8) {
    int s = srcs[p];
    float e = as2[s] + adv;
    e = e > 0.f ? e : 0.2f * e;
    float ex = __expf(e);
    l += ex;
    float4 hv = *(const float4*)(h2 + s * OUTD + fl * 4);
    acc.x += ex * hv.x; acc.y += ex * hv.y;
    acc.z += ex * hv.z; acc.w += ex * hv.w;
  }
  // combine the 8 octants (lane bits 3,4,5)
#pragma unroll
  for (int off = 8; off <= 32; off <<= 1) {
    acc.x += __shfl_xor(acc.x, off, 64);
    acc.y += __shfl_xor(acc.y, off, 64);
    acc.z += __shfl_xor(acc.z, off, 64);
    acc.w += __shfl_xor(acc.w, off, 64);
    l     += __shfl_xor(l,     off, 64);
  }
  if (oc == 0) {
    float li = 1.f / (l + 1e-16f);
    float4 bv = *(const float4*)(b2v + fl * 4);
    float4 mv = *(const float4*)(m + fl * 4);
    float4 vv = *(const float4*)(v + fl * 4);
    float4 gv = *(const float4*)(g + fl * 4);
    float4 bbv = *(const float4*)(bb + fl * 4);
    float4 o;
    o.x = fmaxf((acc.x * li + bv.x - mv.x) * rsqrtf(vv.x + 1e-5f) * gv.x + bbv.x, 0.f);
    o.y = fmaxf((acc.y * li + bv.y - mv.y) * rsqrtf(vv.y + 1e-5f) * gv.y + bbv.y, 0.f);
    o.z = fmaxf((acc.z * li + bv.z - mv.z) * rsqrtf(vv.z + 1e-5f) * gv.z + bbv.z, 0.f);
    o.w = fmaxf((acc.w * li + bv.w - mv.w) * rsqrtf(vv.w + 1e-5f) * gv.w + bbv.w, 0.f);
    *(float4*)(out_emb + node * OUTD + fl * 4) = o;
  }
}

// ---------- classifier + regressor heads (thread per node) ----------
__global__ __launch_bounds__(256) void k_mlp(
    const float* __restrict__ embf,
    const float* __restrict__ cw1, const float* __restrict__ cb1,
    const float* __restrict__ cw2, const float* __restrict__ cb2,
    const float* __restrict__ rw1, const float* __restrict__ rb1,
    const float* __restrict__ rw2, const float* __restrict__ rb2,
    float* __restrict__ out_roles, float* __restrict__ out_energy) {
  __shared__ float C1[OUTD * HID2D], R1[OUTD * HID2D];
  __shared__ float C2[HID2D * 3], CB1[HID2D], RB1[HID2D], R2[HID2D];
  __shared__ float CB2v[3], RB2v;
  int t = threadIdx.x;
  for (int i = t; i < OUTD * HID2D; i += 256) { C1[i] = cw1[i]; R1[i] = rw1[i]; }
  if (t < HID2D) { CB1[t] = cb1[t]; RB1[t] = rb1[t]; R2[t] = rw2[t]; }
  if (t < HID2D * 3) C2[t] = cw2[t];
  if (t < 3) CB2v[t] = cb2[t];
  if (t == 0) RB2v = rb2[0];
  __syncthreads();
  int node = blockIdx.x * 256 + t;
  if (node >= NN) return;
  float e[OUTD];
#pragma unroll
  for (int k = 0; k < OUTD; k++) e[k] = embf[node * OUTD + k];
  float r0 = CB2v[0], r1 = CB2v[1], r2 = CB2v[2], en = RB2v;
  for (int j = 0; j < HID2D; j++) {
    float hc = CB1[j], hr = RB1[j];
#pragma unroll
    for (int k = 0; k < OUTD; k++) {
      hc += e[k] * C1[k * HID2D + j];
      hr += e[k] * R1[k * HID2D + j];
    }
    hc = fmaxf(hc, 0.f);
    hr = fmaxf(hr, 0.f);
    r0 += hc * C2[j * 3 + 0];
    r1 += hc * C2[j * 3 + 1];
    r2 += hc * C2[j * 3 + 2];
    en += hr * R2[j];
  }
  out_roles[node * 3 + 0] = r0;
  out_roles[node * 3 + 1] = r1;
  out_roles[node * 3 + 2] = r2;
  out_energy[node] = en;
}

extern "C" void kernel_launch(void* const* d_in, const int* in_sizes, int n_in,
                              void* d_out, int out_size, void* d_ws, size_t ws_size,
                              hipStream_t stream) {
  const float* x    = (const float*)d_in[0];
  const int*   ei   = (const int*)d_in[1];
  const float* W1   = (const float*)d_in[2];
  const float* as1w = (const float*)d_in[3];
  const float* ad1w = (const float*)d_in[4];
  const float* b1   = (const float*)d_in[5];
  const float* W2   = (const float*)d_in[6];
  const float* as2w = (const float*)d_in[7];
  const float* ad2w = (const float*)d_in[8];
  const float* b2v  = (const float*)d_in[9];
  const float* bn1g = (const float*)d_in[10];
  const float* bn1b = (const float*)d_in[11];
  const float* bn1m = (const float*)d_in[12];
  const float* bn1v = (const float*)d_in[13];
  const float* bn2g = (const float*)d_in[14];
  const float* bn2b = (const float*)d_in[15];
  const float* bn2m = (const float*)d_in[16];
  const float* bn2v = (const float*)d_in[17];
  const float* cw1  = (const float*)d_in[18];
  const float* cb1  = (const float*)d_in[19];
  const float* cw2  = (const float*)d_in[20];
  const float* cb2  = (const float*)d_in[21];
  const float* rw1  = (const float*)d_in[22];
  const float* rb1  = (const float*)d_in[23];
  const float* rw2  = (const float*)d_in[24];
  const float* rb2  = (const float*)d_in[25];

  // workspace layout (~62 MB)
  float* ws  = (float*)d_ws;
  float* h1  = ws;                        // N*64
  float* hbn = h1 + NN * HIDD;            // N*64
  float* as1 = hbn + NN * HIDD;           // N*4
  float* ad1 = as1 + NN * NHEADS;         // N*4
  int* deg   = (int*)(ad1 + NN * NHEADS); // N
  int* rowp  = deg + NN;                  // N+1
  int* cur   = rowp + NN + 1;             // N
  int* bsum  = cur + NN;                  // 1024
  int* srcs  = bsum + 1024;               // ETOT
  float* h2   = h1;                       // N*32 fits in h1's slot
  float* as2  = as1;
  float* ad2  = ad1;

  float* out        = (float*)d_out;
  float* out_emb    = out;                   // N*32
  float* out_roles  = out + NN * OUTD;       // N*3
  float* out_energy = out + NN * (OUTD + 3); // N*1

  hipMemsetAsync(deg, 0, NN * sizeof(int), stream);
  k_lin1<<<NN / 4, 256, 0, stream>>>(x, W1, as1w, ad1w, h1, as1, ad1);
  k_hist<<<(ETOT + 255) / 256, 256, 0, stream>>>(ei, deg);
  k_scan1<<<NBLK, 256, 0, stream>>>(deg, rowp, bsum);
  k_scan2<<<1, 512, 0, stream>>>(bsum);
  k_scan3<<<NBLK, 256, 0, stream>>>(rowp, bsum, cur);
  k_scatter<<<(ETOT + 255) / 256, 256, 0, stream>>>(ei, cur, srcs);
  k_agg1<<<NN / 4, 256, 0, stream>>>(rowp, srcs, h1, as1, ad1, b1, bn1g, bn1b, bn1m, bn1v, hbn);
  k_lin2<<<NN / 8, 256, 0, stream>>>(hbn, W2, as2w, ad2w, h2, as2, ad2);
  k_agg2<<<NN / 4, 256, 0, stream>>>(rowp, srcs, h2, as2, ad2, b2v, bn2g, bn2b, bn2m, bn2v, out_emb);
  k_mlp<<<(NN + 255) / 256, 256, 0, stream>>>(out_emb, cw1, cb1, cw2, cb2, rw1, rb1, rw2, rb2, out_roles, out_energy);
}

// Round 4
// 392.828 us; speedup vs baseline: 1.7095x; 1.3594x over previous
//
#include <hip/hip_runtime.h>

#define NN 100000
#define EE 1600000
#define ETOT (EE + NN)          // 1,700,000 edges incl. self-loops
#define IND 32
#define HIDD 64
#define NHEADS 4
#define OUTD 32
#define HID2D 32

#define BSH 9                   // 512 nodes per bucket
#define NBUCK 196               // ceil(NN / 512)
#define CAP 10240               // max edges per bucket (mean ~8675, sigma ~93)
#define EPB 2048                // edges per k_bin block

// ---------- linear 1: h1 = x @ W1 ; as1/ad1 = per-head attention dots ----------
__global__ __launch_bounds__(256) void k_lin1(
    const float* __restrict__ x, const float* __restrict__ W1,
    const float* __restrict__ atsrc, const float* __restrict__ atdst,
    float* __restrict__ h1, float* __restrict__ as1, float* __restrict__ ad1) {
  __shared__ float Ws[IND * HIDD];
  __shared__ float xs[4 * IND];
  __shared__ float atS[HIDD], atD[HIDD];
  int t = threadIdx.x;
  for (int i = t; i < IND * HIDD; i += 256) Ws[i] = W1[i];
  if (t < HIDD) { atS[t] = atsrc[t]; atD[t] = atdst[t]; }
  if (t < 128) xs[t] = x[blockIdx.x * 128 + t];
  __syncthreads();
  int nl = t >> 6, j = t & 63;
  int node = blockIdx.x * 4 + nl;
  float acc = 0.f;
#pragma unroll
  for (int k = 0; k < IND; k++) acc += xs[nl * IND + k] * Ws[k * HIDD + j];
  h1[node * HIDD + j] = acc;
  float ps = acc * atS[j], pd = acc * atD[j];
#pragma unroll
  for (int off = 8; off >= 1; off >>= 1) {
    ps += __shfl_down(ps, off, 16);
    pd += __shfl_down(pd, off, 16);
  }
  if ((j & 15) == 0) {
    as1[node * NHEADS + (j >> 4)] = ps;
    ad1[node * NHEADS + (j >> 4)] = pd;
  }
}

// ---------- linear 2: h2 = hbn @ W2 ; as2/ad2 ----------
__global__ __launch_bounds__(256) void k_lin2(
    const float* __restrict__ hbn, const float* __restrict__ W2,
    const float* __restrict__ atsrc, const float* __restrict__ atdst,
    float* __restrict__ h2, float* __restrict__ as2, float* __restrict__ ad2) {
  __shared__ float Ws[HIDD * OUTD];
  __shared__ float xs[8 * HIDD];
  __shared__ float atS[OUTD], atD[OUTD];
  int t = threadIdx.x;
  for (int i = t; i < HIDD * OUTD; i += 256) Ws[i] = W2[i];
  if (t < OUTD) { atS[t] = atsrc[t]; atD[t] = atdst[t]; }
  for (int i = t; i < 8 * HIDD; i += 256) xs[i] = hbn[blockIdx.x * 8 * HIDD + i];
  __syncthreads();
  int nl = t >> 5, j = t & 31;
  int node = blockIdx.x * 8 + nl;
  float acc = 0.f;
#pragma unroll
  for (int k = 0; k < HIDD; k++) acc += xs[nl * HIDD + k] * Ws[k * OUTD + j];
  h2[node * OUTD + j] = acc;
  float ps = acc * atS[j], pd = acc * atD[j];
#pragma unroll
  for (int off = 16; off >= 1; off >>= 1) {
    ps += __shfl_down(ps, off, 32);
    pd += __shfl_down(pd, off, 32);
  }
  if (j == 0) { as2[node] = ps; ad2[node] = pd; }
}

// ---------- pass 1: bucket edges by dst>>9; record = (src<<9)|(dst&511) ----------
__global__ __launch_bounds__(256) void k_bin(const int* __restrict__ ei,
                                             int* __restrict__ bcur,
                                             int* __restrict__ bins) {
  __shared__ int cnt[NBUCK];
  int t = threadIdx.x;
  for (int i = t; i < NBUCK; i += 256) cnt[i] = 0;
  __syncthreads();
  int base = blockIdx.x * EPB;
  int recs[8], bks[8];
#pragma unroll
  for (int k = 0; k < 8; k++) {
    int i = base + k * 256 + t;
    recs[k] = -1; bks[k] = 0;
    if (i < ETOT) {
      int s, d;
      if (i < EE) { s = ei[i]; d = ei[EE + i]; } else { s = i - EE; d = s; }
      recs[k] = (s << BSH) | (d & ((1 << BSH) - 1));
      bks[k] = d >> BSH;
      atomicAdd(&cnt[bks[k]], 1);
    }
  }
  __syncthreads();
  // reserve this block's range in each bucket; cnt becomes the running cursor
  for (int i = t; i < NBUCK; i += 256) cnt[i] = atomicAdd(&bcur[i], cnt[i]);
  __syncthreads();
#pragma unroll
  for (int k = 0; k < 8; k++) {
    if (recs[k] >= 0) {
      int pos = atomicAdd(&cnt[bks[k]], 1);
      bins[bks[k] * CAP + pos] = recs[k];
    }
  }
}

// ---------- tiny exclusive scan over the 196 bucket counts ----------
__global__ __launch_bounds__(256) void k_scanb(const int* __restrict__ bcur,
                                               int* __restrict__ gbase,
                                               int* __restrict__ rowp) {
  __shared__ int sA[256], sB[256];
  int t = threadIdx.x;
  int v = (t < NBUCK) ? bcur[t] : 0;
  sA[t] = v;
  __syncthreads();
  int* in = sA; int* out = sB;
  for (int off = 1; off < 256; off <<= 1) {
    out[t] = in[t] + ((t >= off) ? in[t - off] : 0);
    __syncthreads();
    int* tmp = in; in = out; out = tmp;
  }
  if (t < NBUCK) gbase[t] = in[t] - v;
  if (t == 0) rowp[NN] = ETOT;
}

// ---------- pass 2: per-bucket local CSR (one block per bucket) ----------
__global__ __launch_bounds__(256) void k_csr(const int* __restrict__ bcur,
                                             const int* __restrict__ gbase,
                                             const int* __restrict__ bins,
                                             int* __restrict__ rowp,
                                             int* __restrict__ srcs) {
  __shared__ int lrec[CAP];
  __shared__ int ldeg[512], sA[512], sB[512];
  int b = blockIdx.x, t = threadIdx.x;
  int count = bcur[b]; if (count > CAP) count = CAP;
  int gb = gbase[b];
  for (int i = t; i < 512; i += 256) ldeg[i] = 0;
  __syncthreads();
  for (int i = t; i < count; i += 256) {
    int r = bins[b * CAP + i];
    lrec[i] = r;
    atomicAdd(&ldeg[r & 511], 1);
  }
  __syncthreads();
  for (int i = t; i < 512; i += 256) sA[i] = ldeg[i];
  __syncthreads();
  int* in = sA; int* out = sB;
  for (int off = 1; off < 512; off <<= 1) {
    for (int i = t; i < 512; i += 256)
      out[i] = in[i] + ((i >= off) ? in[i - off] : 0);
    __syncthreads();
    int* tmp = in; in = out; out = tmp;
  }
  int nb = b << BSH;
  for (int i = t; i < 512; i += 256) {
    int ex = in[i] - ldeg[i];          // exclusive scan
    if (nb + i < NN) rowp[nb + i] = gb + ex;
    ldeg[i] = ex;                      // reuse as scatter cursor
  }
  __syncthreads();
  for (int i = t; i < count; i += 256) {
    int r = lrec[i];
    int pos = atomicAdd(&ldeg[r & 511], 1);
    srcs[gb + pos] = r >> BSH;         // writes stay in one 35KB L2-resident window
  }
}

// ---------- GAT1 aggregation + bias + BN1 + ReLU ----------
__global__ __launch_bounds__(256) void k_agg1(
    const int* __restrict__ rowp, const int* __restrict__ srcs,
    const float* __restrict__ h1, const float* __restrict__ as1,
    const float* __restrict__ ad1, const float* __restrict__ b1,
    const float* __restrict__ g, const float* __restrict__ bb,
    const float* __restrict__ m, const float* __restrict__ v,
    float* __restrict__ hbn) {
  int t = threadIdx.x;
  int wid = t >> 6, lane = t & 63;
  int node = blockIdx.x * 4 + wid;
  int q = lane >> 4;         // edge slot within chunk of 4
  int fl = lane & 15;        // feature group: floats fl*4..fl*4+3
  int hd = fl >> 2;          // head of this feature group
  int start = rowp[node], end = rowp[node + 1];
  float adv = ad1[node * NHEADS + hd];
  float4 acc = {0.f, 0.f, 0.f, 0.f};
  float l = 0.f;
  for (int p = start + q; p < end; p += 4) {
    int s = srcs[p];
    float e = as1[s * NHEADS + hd] + adv;
    e = e > 0.f ? e : 0.2f * e;
    float ex = __expf(e);
    l += ex;
    float4 hv = *(const float4*)(h1 + s * HIDD + fl * 4);
    acc.x += ex * hv.x; acc.y += ex * hv.y;
    acc.z += ex * hv.z; acc.w += ex * hv.w;
  }
#pragma unroll
  for (int off = 16; off <= 32; off <<= 1) {
    acc.x += __shfl_xor(acc.x, off, 64);
    acc.y += __shfl_xor(acc.y, off, 64);
    acc.z += __shfl_xor(acc.z, off, 64);
    acc.w += __shfl_xor(acc.w, off, 64);
    l     += __shfl_xor(l,     off, 64);
  }
  if (q == 0) {
    float li = 1.f / (l + 1e-16f);
    float4 bv = *(const float4*)(b1 + fl * 4);
    float4 mv = *(const float4*)(m + fl * 4);
    float4 vv = *(const float4*)(v + fl * 4);
    float4 gv = *(const float4*)(g + fl * 4);
    float4 bbv = *(const float4*)(bb + fl * 4);
    float4 o;
    o.x = fmaxf((acc.x * li + bv.x - mv.x) * rsqrtf(vv.x + 1e-5f) * gv.x + bbv.x, 0.f);
    o.y = fmaxf((acc.y * li + bv.y - mv.y) * rsqrtf(vv.y + 1e-5f) * gv.y + bbv.y, 0.f);
    o.z = fmaxf((acc.z * li + bv.z - mv.z) * rsqrtf(vv.z + 1e-5f) * gv.z + bbv.z, 0.f);
    o.w = fmaxf((acc.w * li + bv.w - mv.w) * rsqrtf(vv.w + 1e-5f) * gv.w + bbv.w, 0.f);
    *(float4*)(hbn + node * HIDD + fl * 4) = o;
  }
}

// ---------- GAT2 aggregation + bias + BN2 + ReLU ----------
__global__ __launch_bounds__(256) void k_agg2(
    const int* __restrict__ rowp, const int* __restrict__ srcs,
    const float* __restrict__ h2, const float* __restrict__ as2,
    const float* __restrict__ ad2, const float* __restrict__ b2v,
    const float* __restrict__ g, const float* __restrict__ bb,
    const float* __restrict__ m, const float* __restrict__ v,
    float* __restrict__ out_emb) {
  int t = threadIdx.x;
  int wid = t >> 6, lane = t & 63;
  int node = blockIdx.x * 4 + wid;
  int oc = lane >> 3;        // edge slot within chunk of 8
  int fl = lane & 7;         // feature group
  int start = rowp[node], end = rowp[node + 1];
  float adv = ad2[node];
  float4 acc = {0.f, 0.f, 0.f, 0.f};
  float l = 0.f;
  for (int p = start + oc; p < end; p += 8) {
    int s = srcs[p];
    float e = as2[s] + adv;
    e = e > 0.f ? e : 0.2f * e;
    float ex = __expf(e);
    l += ex;
    float4 hv = *(const float4*)(h2 + s * OUTD + fl * 4);
    acc.x += ex * hv.x; acc.y += ex * hv.y;
    acc.z += ex * hv.z; acc.w += ex * hv.w;
  }
#pragma unroll
  for (int off = 8; off <= 32; off <<= 1) {
    acc.x += __shfl_xor(acc.x, off, 64);
    acc.y += __shfl_xor(acc.y, off, 64);
    acc.z += __shfl_xor(acc.z, off, 64);
    acc.w += __shfl_xor(acc.w, off, 64);
    l     += __shfl_xor(l,     off, 64);
  }
  if (oc == 0) {
    float li = 1.f / (l + 1e-16f);
    float4 bv = *(const float4*)(b2v + fl * 4);
    float4 mv = *(const float4*)(m + fl * 4);
    float4 vv = *(const float4*)(v + fl * 4);
    float4 gv = *(const float4*)(g + fl * 4);
    float4 bbv = *(const float4*)(bb + fl * 4);
    float4 o;
    o.x = fmaxf((acc.x * li + bv.x - mv.x) * rsqrtf(vv.x + 1e-5f) * gv.x + bbv.x, 0.f);
    o.y = fmaxf((acc.y * li + bv.y - mv.y) * rsqrtf(vv.y + 1e-5f) * gv.y + bbv.y, 0.f);
    o.z = fmaxf((acc.z * li + bv.z - mv.z) * rsqrtf(vv.z + 1e-5f) * gv.z + bbv.z, 0.f);
    o.w = fmaxf((acc.w * li + bv.w - mv.w) * rsqrtf(vv.w + 1e-5f) * gv.w + bbv.w, 0.f);
    *(float4*)(out_emb + node * OUTD + fl * 4) = o;
  }
}

// ---------- classifier + regressor heads (thread per node) ----------
__global__ __launch_bounds__(256) void k_mlp(
    const float* __restrict__ embf,
    const float* __restrict__ cw1, const float* __restrict__ cb1,
    const float* __restrict__ cw2, const float* __restrict__ cb2,
    const float* __restrict__ rw1, const float* __restrict__ rb1,
    const float* __restrict__ rw2, const float* __restrict__ rb2,
    float* __restrict__ out_roles, float* __restrict__ out_energy) {
  __shared__ float C1[OUTD * HID2D], R1[OUTD * HID2D];
  __shared__ float C2[HID2D * 3], CB1[HID2D], RB1[HID2D], R2[HID2D];
  __shared__ float CB2v[3], RB2v;
  int t = threadIdx.x;
  for (int i = t; i < OUTD * HID2D; i += 256) { C1[i] = cw1[i]; R1[i] = rw1[i]; }
  if (t < HID2D) { CB1[t] = cb1[t]; RB1[t] = rb1[t]; R2[t] = rw2[t]; }
  if (t < HID2D * 3) C2[t] = cw2[t];
  if (t < 3) CB2v[t] = cb2[t];
  if (t == 0) RB2v = rb2[0];
  __syncthreads();
  int node = blockIdx.x * 256 + t;
  if (node >= NN) return;
  float e[OUTD];
#pragma unroll
  for (int k = 0; k < OUTD; k++) e[k] = embf[node * OUTD + k];
  float r0 = CB2v[0], r1 = CB2v[1], r2 = CB2v[2], en = RB2v;
  for (int j = 0; j < HID2D; j++) {
    float hc = CB1[j], hr = RB1[j];
#pragma unroll
    for (int k = 0; k < OUTD; k++) {
      hc += e[k] * C1[k * HID2D + j];
      hr += e[k] * R1[k * HID2D + j];
    }
    hc = fmaxf(hc, 0.f);
    hr = fmaxf(hr, 0.f);
    r0 += hc * C2[j * 3 + 0];
    r1 += hc * C2[j * 3 + 1];
    r2 += hc * C2[j * 3 + 2];
    en += hr * R2[j];
  }
  out_roles[node * 3 + 0] = r0;
  out_roles[node * 3 + 1] = r1;
  out_roles[node * 3 + 2] = r2;
  out_energy[node] = en;
}

extern "C" void kernel_launch(void* const* d_in, const int* in_sizes, int n_in,
                              void* d_out, int out_size, void* d_ws, size_t ws_size,
                              hipStream_t stream) {
  const float* x    = (const float*)d_in[0];
  const int*   ei   = (const int*)d_in[1];
  const float* W1   = (const float*)d_in[2];
  const float* as1w = (const float*)d_in[3];
  const float* ad1w = (const float*)d_in[4];
  const float* b1   = (const float*)d_in[5];
  const float* W2   = (const float*)d_in[6];
  const float* as2w = (const float*)d_in[7];
  const float* ad2w = (const float*)d_in[8];
  const float* b2v  = (const float*)d_in[9];
  const float* bn1g = (const float*)d_in[10];
  const float* bn1b = (const float*)d_in[11];
  const float* bn1m = (const float*)d_in[12];
  const float* bn1v = (const float*)d_in[13];
  const float* bn2g = (const float*)d_in[14];
  const float* bn2b = (const float*)d_in[15];
  const float* bn2m = (const float*)d_in[16];
  const float* bn2v = (const float*)d_in[17];
  const float* cw1  = (const float*)d_in[18];
  const float* cb1  = (const float*)d_in[19];
  const float* cw2  = (const float*)d_in[20];
  const float* cb2  = (const float*)d_in[21];
  const float* rw1  = (const float*)d_in[22];
  const float* rb1  = (const float*)d_in[23];
  const float* rw2  = (const float*)d_in[24];
  const float* rb2  = (const float*)d_in[25];

  // workspace layout (~62 MB); bins aliases hbn (dead before agg1 writes hbn)
  float* ws  = (float*)d_ws;
  float* h1  = ws;                        // N*64
  float* hbn = h1 + NN * HIDD;            // N*64 (aliased by bins during CSR build)
  float* as1 = hbn + NN * HIDD;           // N*4
  float* ad1 = as1 + NN * NHEADS;         // N*4
  int* rowp  = (int*)(ad1 + NN * NHEADS); // N+1
  int* srcs  = rowp + NN + 1;             // ETOT
  int* bcur  = srcs + ETOT;               // 256
  int* gbase = bcur + 256;                // 256
  int* bins  = (int*)hbn;                 // NBUCK*CAP = 2.0M ints (8MB < 25.6MB slot)
  float* h2   = h1;                       // N*32 fits in h1's slot
  float* as2  = as1;
  float* ad2  = ad1;

  float* out        = (float*)d_out;
  float* out_emb    = out;                   // N*32
  float* out_roles  = out + NN * OUTD;       // N*3
  float* out_energy = out + NN * (OUTD + 3); // N*1

  hipMemsetAsync(bcur, 0, NBUCK * sizeof(int), stream);
  k_bin<<<(ETOT + EPB - 1) / EPB, 256, 0, stream>>>(ei, bcur, bins);
  k_scanb<<<1, 256, 0, stream>>>(bcur, gbase, rowp);
  k_csr<<<NBUCK, 256, 0, stream>>>(bcur, gbase, bins, rowp, srcs);
  k_lin1<<<NN / 4, 256, 0, stream>>>(x, W1, as1w, ad1w, h1, as1, ad1);
  k_agg1<<<NN / 4, 256, 0, stream>>>(rowp, srcs, h1, as1, ad1, b1, bn1g, bn1b, bn1m, bn1v, hbn);
  k_lin2<<<NN / 8, 256, 0, stream>>>(hbn, W2, as2w, ad2w, h2, as2, ad2);
  k_agg2<<<NN / 4, 256, 0, stream>>>(rowp, srcs, h2, as2, ad2, b2v, bn2g, bn2b, bn2m, bn2v, out_emb);
  k_mlp<<<(NN + 255) / 256, 256, 0, stream>>>(out_emb, cw1, cb1, cw2, cb2, rw1, rb1, rw2, rb2, out_roles, out_energy);
}

// Round 5
// 363.002 us; speedup vs baseline: 1.8500x; 1.0822x over previous
//
#include <hip/hip_runtime.h>
#include <hip/hip_bf16.h>

#define NN 100000
#define EE 1600000
#define ETOT (EE + NN)          // 1,700,000 edges incl. self-loops
#define IND 32
#define HIDD 64
#define NHEADS 4
#define OUTD 32
#define HID2D 32

#define BSH 9                   // 512 nodes per bucket
#define NBUCK 196               // ceil(NN / 512)
#define CAP 10240               // max edges per bucket (mean ~8675)
#define EPB 2048                // edges per k_bin block

typedef unsigned int uint;

__device__ __forceinline__ uint pack2(float a, float b) {
  uint lo = (uint)__bfloat16_as_ushort(__float2bfloat16(a));
  uint hi = (uint)__bfloat16_as_ushort(__float2bfloat16(b));
  return (hi << 16) | lo;
}
__device__ __forceinline__ float lo2f(uint w) { return __uint_as_float(w << 16); }
__device__ __forceinline__ float hi2f(uint w) { return __uint_as_float(w & 0xFFFF0000u); }

// ---------- linear 1: h1(bf16) = x @ W1 ; as1/ad1 f32 attention dots ----------
// 8 nodes/block, 32 threads/node, 2 features/thread (packed to one uint)
__global__ __launch_bounds__(256) void k_lin1(
    const float* __restrict__ x, const float* __restrict__ W1,
    const float* __restrict__ atsrc, const float* __restrict__ atdst,
    uint* __restrict__ h1u, float* __restrict__ as1, float* __restrict__ ad1) {
  __shared__ float Ws[IND * HIDD];
  __shared__ float xs[8 * IND];
  __shared__ float atS[HIDD], atD[HIDD];
  int t = threadIdx.x;
  for (int i = t; i < IND * HIDD; i += 256) Ws[i] = W1[i];
  if (t < HIDD) { atS[t] = atsrc[t]; atD[t] = atdst[t]; }
  xs[t] = x[blockIdx.x * 256 + t];
  __syncthreads();
  int nl = t >> 5, tl = t & 31;
  int node = blockIdx.x * 8 + nl;
  int j0 = 2 * tl, j1 = j0 + 1;
  float a0 = 0.f, a1 = 0.f;
#pragma unroll
  for (int k = 0; k < IND; k++) {
    float xv = xs[nl * IND + k];
    a0 += xv * Ws[k * HIDD + j0];
    a1 += xv * Ws[k * HIDD + j1];
  }
  h1u[node * 32 + tl] = pack2(a0, a1);
  float ps = a0 * atS[j0] + a1 * atS[j1];
  float pd = a0 * atD[j0] + a1 * atD[j1];
#pragma unroll
  for (int off = 4; off >= 1; off >>= 1) {
    ps += __shfl_down(ps, off, 8);
    pd += __shfl_down(pd, off, 8);
  }
  if ((tl & 7) == 0) {
    as1[node * NHEADS + (tl >> 3)] = ps;
    ad1[node * NHEADS + (tl >> 3)] = pd;
  }
}

// ---------- linear 2: h2(bf16) = hbn(f32) @ W2 ; as2/ad2 ----------
// 16 nodes/block, 16 threads/node, 2 features/thread
__global__ __launch_bounds__(256) void k_lin2(
    const float* __restrict__ hbn, const float* __restrict__ W2,
    const float* __restrict__ atsrc, const float* __restrict__ atdst,
    uint* __restrict__ h2u, float* __restrict__ as2, float* __restrict__ ad2) {
  __shared__ float Ws[HIDD * OUTD];
  __shared__ float xs[16 * HIDD];
  __shared__ float atS[OUTD], atD[OUTD];
  int t = threadIdx.x;
  for (int i = t; i < HIDD * OUTD; i += 256) Ws[i] = W2[i];
  if (t < OUTD) { atS[t] = atsrc[t]; atD[t] = atdst[t]; }
  for (int i = t; i < 16 * HIDD; i += 256) xs[i] = hbn[blockIdx.x * 16 * HIDD + i];
  __syncthreads();
  int nl = t >> 4, tl = t & 15;
  int node = blockIdx.x * 16 + nl;
  int j0 = 2 * tl, j1 = j0 + 1;
  float a0 = 0.f, a1 = 0.f;
#pragma unroll
  for (int k = 0; k < HIDD; k++) {
    float xv = xs[nl * HIDD + k];
    a0 += xv * Ws[k * OUTD + j0];
    a1 += xv * Ws[k * OUTD + j1];
  }
  h2u[node * 16 + tl] = pack2(a0, a1);
  float ps = a0 * atS[j0] + a1 * atS[j1];
  float pd = a0 * atD[j0] + a1 * atD[j1];
#pragma unroll
  for (int off = 8; off >= 1; off >>= 1) {
    ps += __shfl_down(ps, off, 16);
    pd += __shfl_down(pd, off, 16);
  }
  if (tl == 0) { as2[node] = ps; ad2[node] = pd; }
}

// ---------- pass 1: bucket edges by dst>>9; record = (src<<9)|(dst&511) ----------
__global__ __launch_bounds__(256) void k_bin(const int* __restrict__ ei,
                                             int* __restrict__ bcur,
                                             int* __restrict__ bins) {
  __shared__ int cnt[NBUCK];
  int t = threadIdx.x;
  for (int i = t; i < NBUCK; i += 256) cnt[i] = 0;
  __syncthreads();
  int base = blockIdx.x * EPB;
  int recs[8], bks[8];
#pragma unroll
  for (int k = 0; k < 8; k++) {
    int i = base + k * 256 + t;
    recs[k] = -1; bks[k] = 0;
    if (i < ETOT) {
      int s, d;
      if (i < EE) { s = ei[i]; d = ei[EE + i]; } else { s = i - EE; d = s; }
      recs[k] = (s << BSH) | (d & ((1 << BSH) - 1));
      bks[k] = d >> BSH;
      atomicAdd(&cnt[bks[k]], 1);
    }
  }
  __syncthreads();
  for (int i = t; i < NBUCK; i += 256) cnt[i] = atomicAdd(&bcur[i], cnt[i]);
  __syncthreads();
#pragma unroll
  for (int k = 0; k < 8; k++) {
    if (recs[k] >= 0) {
      int pos = atomicAdd(&cnt[bks[k]], 1);
      bins[bks[k] * CAP + pos] = recs[k];
    }
  }
}

// ---------- tiny exclusive scan over the 196 bucket counts ----------
__global__ __launch_bounds__(256) void k_scanb(const int* __restrict__ bcur,
                                               int* __restrict__ gbase,
                                               int* __restrict__ rowp) {
  __shared__ int sA[256], sB[256];
  int t = threadIdx.x;
  int v = (t < NBUCK) ? bcur[t] : 0;
  sA[t] = v;
  __syncthreads();
  int* in = sA; int* out = sB;
  for (int off = 1; off < 256; off <<= 1) {
    out[t] = in[t] + ((t >= off) ? in[t - off] : 0);
    __syncthreads();
    int* tmp = in; in = out; out = tmp;
  }
  if (t < NBUCK) gbase[t] = in[t] - v;
  if (t == 0) rowp[NN] = ETOT;
}

// ---------- pass 2: per-bucket local CSR (one block per bucket) ----------
__global__ __launch_bounds__(256) void k_csr(const int* __restrict__ bcur,
                                             const int* __restrict__ gbase,
                                             const int* __restrict__ bins,
                                             int* __restrict__ rowp,
                                             int* __restrict__ srcs) {
  __shared__ int lrec[CAP];
  __shared__ int ldeg[512], sA[512], sB[512];
  int b = blockIdx.x, t = threadIdx.x;
  int count = bcur[b]; if (count > CAP) count = CAP;
  int gb = gbase[b];
  for (int i = t; i < 512; i += 256) ldeg[i] = 0;
  __syncthreads();
  for (int i = t; i < count; i += 256) {
    int r = bins[b * CAP + i];
    lrec[i] = r;
    atomicAdd(&ldeg[r & 511], 1);
  }
  __syncthreads();
  for (int i = t; i < 512; i += 256) sA[i] = ldeg[i];
  __syncthreads();
  int* in = sA; int* out = sB;
  for (int off = 1; off < 512; off <<= 1) {
    for (int i = t; i < 512; i += 256)
      out[i] = in[i] + ((i >= off) ? in[i - off] : 0);
    __syncthreads();
    int* tmp = in; in = out; out = tmp;
  }
  int nb = b << BSH;
  for (int i = t; i < 512; i += 256) {
    int ex = in[i] - ldeg[i];          // exclusive scan
    if (nb + i < NN) rowp[nb + i] = gb + ex;
    ldeg[i] = ex;                      // reuse as scatter cursor
  }
  __syncthreads();
  for (int i = t; i < count; i += 256) {
    int r = lrec[i];
    int pos = atomicAdd(&ldeg[r & 511], 1);
    srcs[gb + pos] = r >> BSH;
  }
}

// ---------- GAT1 aggregation + bias + BN1 + ReLU ----------
// wave per node; 8 edge slots x 8 lanes; lane reads uint4 = 8 bf16 features
__global__ __launch_bounds__(256) void k_agg1(
    const int* __restrict__ rowp, const int* __restrict__ srcs,
    const uint* __restrict__ h1u, const float* __restrict__ as1,
    const float* __restrict__ ad1, const float* __restrict__ b1,
    const float* __restrict__ g, const float* __restrict__ bb,
    const float* __restrict__ m, const float* __restrict__ v,
    float* __restrict__ hbn) {
  int t = threadIdx.x;
  int wid = t >> 6, lane = t & 63;
  int node = blockIdx.x * 4 + wid;
  int slot = lane >> 3;      // edge slot (8)
  int fl = lane & 7;         // feature group: feats fl*8..fl*8+7
  int hd = fl >> 1;          // 16 feats/head, 8-blocks stay in one head
  int start = rowp[node], end = rowp[node + 1];
  float adv = ad1[node * NHEADS + hd];
  const uint4* h14 = (const uint4*)h1u;
  float acc[8] = {0.f, 0.f, 0.f, 0.f, 0.f, 0.f, 0.f, 0.f};
  float l = 0.f;
  for (int p = start + slot; p < end; p += 8) {
    int s = srcs[p];
    float e = as1[s * NHEADS + hd] + adv;
    e = e > 0.f ? e : 0.2f * e;
    float ex = __expf(e);
    l += ex;
    uint4 w = h14[s * 8 + fl];
    acc[0] += ex * lo2f(w.x); acc[1] += ex * hi2f(w.x);
    acc[2] += ex * lo2f(w.y); acc[3] += ex * hi2f(w.y);
    acc[4] += ex * lo2f(w.z); acc[5] += ex * hi2f(w.z);
    acc[6] += ex * lo2f(w.w); acc[7] += ex * hi2f(w.w);
  }
#pragma unroll
  for (int off = 8; off <= 32; off <<= 1) {
#pragma unroll
    for (int i = 0; i < 8; i++) acc[i] += __shfl_xor(acc[i], off, 64);
    l += __shfl_xor(l, off, 64);
  }
  if (slot == 0) {
    float li = 1.f / (l + 1e-16f);
    int fb = fl * 8;
    float o[8];
#pragma unroll
    for (int i = 0; i < 8; i++) {
      int j = fb + i;
      float ov = acc[i] * li + b1[j];
      ov = (ov - m[j]) * rsqrtf(v[j] + 1e-5f) * g[j] + bb[j];
      o[i] = fmaxf(ov, 0.f);
    }
    float4* dst = (float4*)(hbn + node * HIDD + fb);
    dst[0] = make_float4(o[0], o[1], o[2], o[3]);
    dst[1] = make_float4(o[4], o[5], o[6], o[7]);
  }
}

// ---------- GAT2 aggregation + bias + BN2 + ReLU ----------
// wave per node; 16 edge slots x 4 lanes; lane reads uint4 = 8 bf16 features
__global__ __launch_bounds__(256) void k_agg2(
    const int* __restrict__ rowp, const int* __restrict__ srcs,
    const uint* __restrict__ h2u, const float* __restrict__ as2,
    const float* __restrict__ ad2, const float* __restrict__ b2v,
    const float* __restrict__ g, const float* __restrict__ bb,
    const float* __restrict__ m, const float* __restrict__ v,
    float* __restrict__ out_emb) {
  int t = threadIdx.x;
  int wid = t >> 6, lane = t & 63;
  int node = blockIdx.x * 4 + wid;
  int slot = lane >> 2;      // edge slot (16)
  int fl = lane & 3;         // feature group: feats fl*8..fl*8+7
  int start = rowp[node], end = rowp[node + 1];
  float adv = ad2[node];
  const uint4* h24 = (const uint4*)h2u;
  float acc[8] = {0.f, 0.f, 0.f, 0.f, 0.f, 0.f, 0.f, 0.f};
  float l = 0.f;
  for (int p = start + slot; p < end; p += 16) {
    int s = srcs[p];
    float e = as2[s] + adv;
    e = e > 0.f ? e : 0.2f * e;
    float ex = __expf(e);
    l += ex;
    uint4 w = h24[s * 4 + fl];
    acc[0] += ex * lo2f(w.x); acc[1] += ex * hi2f(w.x);
    acc[2] += ex * lo2f(w.y); acc[3] += ex * hi2f(w.y);
    acc[4] += ex * lo2f(w.z); acc[5] += ex * hi2f(w.z);
    acc[6] += ex * lo2f(w.w); acc[7] += ex * hi2f(w.w);
  }
#pragma unroll
  for (int off = 4; off <= 32; off <<= 1) {
#pragma unroll
    for (int i = 0; i < 8; i++) acc[i] += __shfl_xor(acc[i], off, 64);
    l += __shfl_xor(l, off, 64);
  }
  if (slot == 0) {
    float li = 1.f / (l + 1e-16f);
    int fb = fl * 8;
    float o[8];
#pragma unroll
    for (int i = 0; i < 8; i++) {
      int j = fb + i;
      float ov = acc[i] * li + b2v[j];
      ov = (ov - m[j]) * rsqrtf(v[j] + 1e-5f) * g[j] + bb[j];
      o[i] = fmaxf(ov, 0.f);
    }
    float4* dst = (float4*)(out_emb + node * OUTD + fb);
    dst[0] = make_float4(o[0], o[1], o[2], o[3]);
    dst[1] = make_float4(o[4], o[5], o[6], o[7]);
  }
}

// ---------- classifier + regressor heads (thread per node) ----------
__global__ __launch_bounds__(256) void k_mlp(
    const float* __restrict__ embf,
    const float* __restrict__ cw1, const float* __restrict__ cb1,
    const float* __restrict__ cw2, const float* __restrict__ cb2,
    const float* __restrict__ rw1, const float* __restrict__ rb1,
    const float* __restrict__ rw2, const float* __restrict__ rb2,
    float* __restrict__ out_roles, float* __restrict__ out_energy) {
  __shared__ float C1[OUTD * HID2D], R1[OUTD * HID2D];
  __shared__ float C2[HID2D * 3], CB1[HID2D], RB1[HID2D], R2[HID2D];
  __shared__ float CB2v[3], RB2v;
  int t = threadIdx.x;
  for (int i = t; i < OUTD * HID2D; i += 256) { C1[i] = cw1[i]; R1[i] = rw1[i]; }
  if (t < HID2D) { CB1[t] = cb1[t]; RB1[t] = rb1[t]; R2[t] = rw2[t]; }
  if (t < HID2D * 3) C2[t] = cw2[t];
  if (t < 3) CB2v[t] = cb2[t];
  if (t == 0) RB2v = rb2[0];
  __syncthreads();
  int node = blockIdx.x * 256 + t;
  if (node >= NN) return;
  float e[OUTD];
#pragma unroll
  for (int k = 0; k < OUTD; k++) e[k] = embf[node * OUTD + k];
  float r0 = CB2v[0], r1 = CB2v[1], r2 = CB2v[2], en = RB2v;
  for (int j = 0; j < HID2D; j++) {
    float hc = CB1[j], hr = RB1[j];
#pragma unroll
    for (int k = 0; k < OUTD; k++) {
      hc += e[k] * C1[k * HID2D + j];
      hr += e[k] * R1[k * HID2D + j];
    }
    hc = fmaxf(hc, 0.f);
    hr = fmaxf(hr, 0.f);
    r0 += hc * C2[j * 3 + 0];
    r1 += hc * C2[j * 3 + 1];
    r2 += hc * C2[j * 3 + 2];
    en += hr * R2[j];
  }
  out_roles[node * 3 + 0] = r0;
  out_roles[node * 3 + 1] = r1;
  out_roles[node * 3 + 2] = r2;
  out_energy[node] = en;
}

extern "C" void kernel_launch(void* const* d_in, const int* in_sizes, int n_in,
                              void* d_out, int out_size, void* d_ws, size_t ws_size,
                              hipStream_t stream) {
  const float* x    = (const float*)d_in[0];
  const int*   ei   = (const int*)d_in[1];
  const float* W1   = (const float*)d_in[2];
  const float* as1w = (const float*)d_in[3];
  const float* ad1w = (const float*)d_in[4];
  const float* b1   = (const float*)d_in[5];
  const float* W2   = (const float*)d_in[6];
  const float* as2w = (const float*)d_in[7];
  const float* ad2w = (const float*)d_in[8];
  const float* b2v  = (const float*)d_in[9];
  const float* bn1g = (const float*)d_in[10];
  const float* bn1b = (const float*)d_in[11];
  const float* bn1m = (const float*)d_in[12];
  const float* bn1v = (const float*)d_in[13];
  const float* bn2g = (const float*)d_in[14];
  const float* bn2b = (const float*)d_in[15];
  const float* bn2m = (const float*)d_in[16];
  const float* bn2v = (const float*)d_in[17];
  const float* cw1  = (const float*)d_in[18];
  const float* cb1  = (const float*)d_in[19];
  const float* cw2  = (const float*)d_in[20];
  const float* cb2  = (const float*)d_in[21];
  const float* rw1  = (const float*)d_in[22];
  const float* rb1  = (const float*)d_in[23];
  const float* rw2  = (const float*)d_in[24];
  const float* rb2  = (const float*)d_in[25];

  // workspace (~49 MB); bins aliases hbn (dead before agg1 writes hbn);
  // h2u aliases h1u (h1 dead after agg1)
  uint*  h1u = (uint*)d_ws;               // N*32 uints (bf16x2) = 12.8MB
  float* hbn = (float*)(h1u + NN * 32);   // N*64 f32 = 25.6MB
  float* as1 = hbn + NN * HIDD;           // N*4
  float* ad1 = as1 + NN * NHEADS;         // N*4
  int* rowp  = (int*)(ad1 + NN * NHEADS); // N+1
  int* srcs  = rowp + NN + 1;             // ETOT
  int* bcur  = srcs + ETOT;               // 256
  int* gbase = bcur + 256;                // 256
  int* bins  = (int*)hbn;                 // NBUCK*CAP = 2.0M ints (8MB < 25.6MB)
  uint* h2u  = h1u;                       // N*16 uints fits h1u slot
  float* as2 = as1;
  float* ad2 = ad1;

  float* out        = (float*)d_out;
  float* out_emb    = out;                   // N*32
  float* out_roles  = out + NN * OUTD;       // N*3
  float* out_energy = out + NN * (OUTD + 3); // N*1

  hipMemsetAsync(bcur, 0, NBUCK * sizeof(int), stream);
  k_bin<<<(ETOT + EPB - 1) / EPB, 256, 0, stream>>>(ei, bcur, bins);
  k_scanb<<<1, 256, 0, stream>>>(bcur, gbase, rowp);
  k_csr<<<NBUCK, 256, 0, stream>>>(bcur, gbase, bins, rowp, srcs);
  k_lin1<<<NN / 8, 256, 0, stream>>>(x, W1, as1w, ad1w, h1u, as1, ad1);
  k_agg1<<<NN / 4, 256, 0, stream>>>(rowp, srcs, h1u, as1, ad1, b1, bn1g, bn1b, bn1m, bn1v, hbn);
  k_lin2<<<NN / 16, 256, 0, stream>>>(hbn, W2, as2w, ad2w, h2u, as2, ad2);
  k_agg2<<<NN / 4, 256, 0, stream>>>(rowp, srcs, h2u, as2, ad2, b2v, bn2g, bn2b, bn2m, bn2v, out_emb);
  k_mlp<<<(NN + 255) / 256, 256, 0, stream>>>(out_emb, cw1, cb1, cw2, cb2, rw1, rb1, rw2, rb2, out_roles, out_energy);
}

// Round 6
// 359.859 us; speedup vs baseline: 1.8661x; 1.0087x over previous
//
#include <hip/hip_runtime.h>
#include <hip/hip_bf16.h>

#define NN 100000
#define EE 1600000
#define ETOT (EE + NN)          // 1,700,000 edges incl. self-loops
#define IND 32
#define HIDD 64
#define NHEADS 4
#define OUTD 32
#define HID2D 32

#define BSH 9                   // 512 nodes per bucket
#define NBUCK 196               // ceil(NN / 512)
#define CAP 10240               // max edges per bucket (mean ~8675)
#define EPB 2048                // edges per k_bin block

typedef unsigned int uint;

__device__ __forceinline__ uint pack2(float a, float b) {
  uint lo = (uint)__bfloat16_as_ushort(__float2bfloat16(a));
  uint hi = (uint)__bfloat16_as_ushort(__float2bfloat16(b));
  return (hi << 16) | lo;
}
__device__ __forceinline__ float lo2f(uint w) { return __uint_as_float(w << 16); }
__device__ __forceinline__ float hi2f(uint w) { return __uint_as_float(w & 0xFFFF0000u); }

// ---------- linear 1: h1(bf16) = x @ W1 ; as1/ad1 f32 attention dots ----------
__global__ __launch_bounds__(256) void k_lin1(
    const float* __restrict__ x, const float* __restrict__ W1,
    const float* __restrict__ atsrc, const float* __restrict__ atdst,
    uint* __restrict__ h1u, float* __restrict__ as1, float* __restrict__ ad1) {
  __shared__ float Ws[IND * HIDD];
  __shared__ float xs[8 * IND];
  __shared__ float atS[HIDD], atD[HIDD];
  int t = threadIdx.x;
  for (int i = t; i < IND * HIDD; i += 256) Ws[i] = W1[i];
  if (t < HIDD) { atS[t] = atsrc[t]; atD[t] = atdst[t]; }
  xs[t] = x[blockIdx.x * 256 + t];
  __syncthreads();
  int nl = t >> 5, tl = t & 31;
  int node = blockIdx.x * 8 + nl;
  int j0 = 2 * tl, j1 = j0 + 1;
  float a0 = 0.f, a1 = 0.f;
#pragma unroll
  for (int k = 0; k < IND; k++) {
    float xv = xs[nl * IND + k];
    a0 += xv * Ws[k * HIDD + j0];
    a1 += xv * Ws[k * HIDD + j1];
  }
  h1u[node * 32 + tl] = pack2(a0, a1);
  float ps = a0 * atS[j0] + a1 * atS[j1];
  float pd = a0 * atD[j0] + a1 * atD[j1];
#pragma unroll
  for (int off = 4; off >= 1; off >>= 1) {
    ps += __shfl_down(ps, off, 8);
    pd += __shfl_down(pd, off, 8);
  }
  if ((tl & 7) == 0) {
    as1[node * NHEADS + (tl >> 3)] = ps;
    ad1[node * NHEADS + (tl >> 3)] = pd;
  }
}

// ---------- linear 2: h2(bf16) = hbn(f32) @ W2 ; as2/ad2 ----------
__global__ __launch_bounds__(256) void k_lin2(
    const float* __restrict__ hbn, const float* __restrict__ W2,
    const float* __restrict__ atsrc, const float* __restrict__ atdst,
    uint* __restrict__ h2u, float* __restrict__ as2, float* __restrict__ ad2) {
  __shared__ float Ws[HIDD * OUTD];
  __shared__ float xs[16 * HIDD];
  __shared__ float atS[OUTD], atD[OUTD];
  int t = threadIdx.x;
  for (int i = t; i < HIDD * OUTD; i += 256) Ws[i] = W2[i];
  if (t < OUTD) { atS[t] = atsrc[t]; atD[t] = atdst[t]; }
  for (int i = t; i < 16 * HIDD; i += 256) xs[i] = hbn[blockIdx.x * 16 * HIDD + i];
  __syncthreads();
  int nl = t >> 4, tl = t & 15;
  int node = blockIdx.x * 16 + nl;
  int j0 = 2 * tl, j1 = j0 + 1;
  float a0 = 0.f, a1 = 0.f;
#pragma unroll
  for (int k = 0; k < HIDD; k++) {
    float xv = xs[nl * HIDD + k];
    a0 += xv * Ws[k * OUTD + j0];
    a1 += xv * Ws[k * OUTD + j1];
  }
  h2u[node * 16 + tl] = pack2(a0, a1);
  float ps = a0 * atS[j0] + a1 * atS[j1];
  float pd = a0 * atD[j0] + a1 * atD[j1];
#pragma unroll
  for (int off = 8; off >= 1; off >>= 1) {
    ps += __shfl_down(ps, off, 16);
    pd += __shfl_down(pd, off, 16);
  }
  if (tl == 0) { as2[node] = ps; ad2[node] = pd; }
}

// ---------- pass 1: bucket edges by dst>>9; record = (src<<9)|(dst&511) ----------
__global__ __launch_bounds__(256) void k_bin(const int* __restrict__ ei,
                                             int* __restrict__ bcur,
                                             int* __restrict__ bins) {
  __shared__ int cnt[NBUCK];
  int t = threadIdx.x;
  for (int i = t; i < NBUCK; i += 256) cnt[i] = 0;
  __syncthreads();
  int base = blockIdx.x * EPB;
  int recs[8], bks[8];
#pragma unroll
  for (int k = 0; k < 8; k++) {
    int i = base + k * 256 + t;
    recs[k] = -1; bks[k] = 0;
    if (i < ETOT) {
      int s, d;
      if (i < EE) { s = ei[i]; d = ei[EE + i]; } else { s = i - EE; d = s; }
      recs[k] = (s << BSH) | (d & ((1 << BSH) - 1));
      bks[k] = d >> BSH;
      atomicAdd(&cnt[bks[k]], 1);
    }
  }
  __syncthreads();
  for (int i = t; i < NBUCK; i += 256) cnt[i] = atomicAdd(&bcur[i], cnt[i]);
  __syncthreads();
#pragma unroll
  for (int k = 0; k < 8; k++) {
    if (recs[k] >= 0) {
      int pos = atomicAdd(&cnt[bks[k]], 1);
      bins[bks[k] * CAP + pos] = recs[k];
    }
  }
}

// ---------- tiny exclusive scan over the 196 bucket counts ----------
__global__ __launch_bounds__(256) void k_scanb(const int* __restrict__ bcur,
                                               int* __restrict__ gbase,
                                               int* __restrict__ rowp) {
  __shared__ int sA[256], sB[256];
  int t = threadIdx.x;
  int v = (t < NBUCK) ? bcur[t] : 0;
  sA[t] = v;
  __syncthreads();
  int* in = sA; int* out = sB;
  for (int off = 1; off < 256; off <<= 1) {
    out[t] = in[t] + ((t >= off) ? in[t - off] : 0);
    __syncthreads();
    int* tmp = in; in = out; out = tmp;
  }
  if (t < NBUCK) gbase[t] = in[t] - v;
  if (t == 0) rowp[NN] = ETOT;
}

// ---------- pass 2: per-bucket local CSR (one block per bucket) ----------
__global__ __launch_bounds__(256) void k_csr(const int* __restrict__ bcur,
                                             const int* __restrict__ gbase,
                                             const int* __restrict__ bins,
                                             int* __restrict__ rowp,
                                             int* __restrict__ srcs) {
  __shared__ int lrec[CAP];
  __shared__ int ldeg[512], sA[512], sB[512];
  int b = blockIdx.x, t = threadIdx.x;
  int count = bcur[b]; if (count > CAP) count = CAP;
  int gb = gbase[b];
  for (int i = t; i < 512; i += 256) ldeg[i] = 0;
  __syncthreads();
  for (int i = t; i < count; i += 256) {
    int r = bins[b * CAP + i];
    lrec[i] = r;
    atomicAdd(&ldeg[r & 511], 1);
  }
  __syncthreads();
  for (int i = t; i < 512; i += 256) sA[i] = ldeg[i];
  __syncthreads();
  int* in = sA; int* out = sB;
  for (int off = 1; off < 512; off <<= 1) {
    for (int i = t; i < 512; i += 256)
      out[i] = in[i] + ((i >= off) ? in[i - off] : 0);
    __syncthreads();
    int* tmp = in; in = out; out = tmp;
  }
  int nb = b << BSH;
  for (int i = t; i < 512; i += 256) {
    int ex = in[i] - ldeg[i];          // exclusive scan
    if (nb + i < NN) rowp[nb + i] = gb + ex;
    ldeg[i] = ex;                      // reuse as scatter cursor
  }
  __syncthreads();
  for (int i = t; i < count; i += 256) {
    int r = lrec[i];
    int pos = atomicAdd(&ldeg[r & 511], 1);
    srcs[gb + pos] = r >> BSH;
  }
}

// ---------- GAT1 aggregation + bias + BN1 + ReLU ----------
// wave per node; 8 edge slots x 8 lanes; lane reads uint4 = 8 bf16 features.
// Depth-2 software pipeline: s fetched 2 iters ahead, h-row/as 1 iter ahead.
__global__ __launch_bounds__(256) void k_agg1(
    const int* __restrict__ rowp, const int* __restrict__ srcs,
    const uint* __restrict__ h1u, const float* __restrict__ as1,
    const float* __restrict__ ad1, const float* __restrict__ b1,
    const float* __restrict__ g, const float* __restrict__ bb,
    const float* __restrict__ m, const float* __restrict__ v,
    float* __restrict__ hbn) {
  int t = threadIdx.x;
  int wid = t >> 6, lane = t & 63;
  int node = blockIdx.x * 4 + wid;
  int slot = lane >> 3;      // edge slot (8)
  int fl = lane & 7;         // feature group: feats fl*8..fl*8+7
  int hd = fl >> 1;
  int start = rowp[node], end = rowp[node + 1];
  int lastp = end - 1;       // deg >= 1 always (self-loop)
  float adv = ad1[node * NHEADS + hd];
  const uint4* h14 = (const uint4*)h1u;
  float acc[8] = {0.f, 0.f, 0.f, 0.f, 0.f, 0.f, 0.f, 0.f};
  float l = 0.f;
  int p = start + slot;
  int pc = p < lastp ? p : lastp;
  int s0 = srcs[pc];
  uint4 w = h14[s0 * 8 + fl];          // row for iter 0
  float as = as1[s0 * NHEADS + hd];
  int p1 = p + 8;
  int pc1 = p1 < lastp ? p1 : lastp;
  int s1 = srcs[pc1];                  // s for iter 1
  while (p < end) {
    // prefetch next iteration's row + logit input (uses s fetched 2 iters back)
    uint4 wn = h14[s1 * 8 + fl];
    float asn = as1[s1 * NHEADS + hd];
    int p2 = p1 + 8;
    int pc2 = p2 < lastp ? p2 : lastp;
    int s2 = srcs[pc2];
    // process current
    float e = as + adv;
    e = fmaxf(e, 0.2f * e);
    float ex = __expf(e);
    l += ex;
    acc[0] += ex * lo2f(w.x); acc[1] += ex * hi2f(w.x);
    acc[2] += ex * lo2f(w.y); acc[3] += ex * hi2f(w.y);
    acc[4] += ex * lo2f(w.z); acc[5] += ex * hi2f(w.z);
    acc[6] += ex * lo2f(w.w); acc[7] += ex * hi2f(w.w);
    // shift pipeline
    w = wn; as = asn; s1 = s2; p = p1; p1 = p2;
  }
#pragma unroll
  for (int off = 8; off <= 32; off <<= 1) {
#pragma unroll
    for (int i = 0; i < 8; i++) acc[i] += __shfl_xor(acc[i], off, 64);
    l += __shfl_xor(l, off, 64);
  }
  if (slot == 0) {
    float li = 1.f / (l + 1e-16f);
    int fb = fl * 8;
    float o[8];
#pragma unroll
    for (int i = 0; i < 8; i++) {
      int j = fb + i;
      float ov = acc[i] * li + b1[j];
      ov = (ov - m[j]) * rsqrtf(v[j] + 1e-5f) * g[j] + bb[j];
      o[i] = fmaxf(ov, 0.f);
    }
    float4* dst = (float4*)(hbn + node * HIDD + fb);
    dst[0] = make_float4(o[0], o[1], o[2], o[3]);
    dst[1] = make_float4(o[4], o[5], o[6], o[7]);
  }
}

// ---------- GAT2 aggregation + bias + BN2 + ReLU ----------
// wave per node; 8 edge slots x 8 lanes; lane reads uint2 = 4 bf16 features.
__global__ __launch_bounds__(256) void k_agg2(
    const int* __restrict__ rowp, const int* __restrict__ srcs,
    const uint* __restrict__ h2u, const float* __restrict__ as2,
    const float* __restrict__ ad2, const float* __restrict__ b2v,
    const float* __restrict__ g, const float* __restrict__ bb,
    const float* __restrict__ m, const float* __restrict__ v,
    float* __restrict__ out_emb) {
  int t = threadIdx.x;
  int wid = t >> 6, lane = t & 63;
  int node = blockIdx.x * 4 + wid;
  int slot = lane >> 3;      // edge slot (8)
  int fl = lane & 7;         // feature group: feats fl*4..fl*4+3
  int start = rowp[node], end = rowp[node + 1];
  int lastp = end - 1;
  float adv = ad2[node];
  const uint2* h22 = (const uint2*)h2u;
  float acc[4] = {0.f, 0.f, 0.f, 0.f};
  float l = 0.f;
  int p = start + slot;
  int pc = p < lastp ? p : lastp;
  int s0 = srcs[pc];
  uint2 w = h22[s0 * 8 + fl];
  float as = as2[s0];
  int p1 = p + 8;
  int pc1 = p1 < lastp ? p1 : lastp;
  int s1 = srcs[pc1];
  while (p < end) {
    uint2 wn = h22[s1 * 8 + fl];
    float asn = as2[s1];
    int p2 = p1 + 8;
    int pc2 = p2 < lastp ? p2 : lastp;
    int s2 = srcs[pc2];
    float e = as + adv;
    e = fmaxf(e, 0.2f * e);
    float ex = __expf(e);
    l += ex;
    acc[0] += ex * lo2f(w.x); acc[1] += ex * hi2f(w.x);
    acc[2] += ex * lo2f(w.y); acc[3] += ex * hi2f(w.y);
    w = wn; as = asn; s1 = s2; p = p1; p1 = p2;
  }
#pragma unroll
  for (int off = 8; off <= 32; off <<= 1) {
#pragma unroll
    for (int i = 0; i < 4; i++) acc[i] += __shfl_xor(acc[i], off, 64);
    l += __shfl_xor(l, off, 64);
  }
  if (slot == 0) {
    float li = 1.f / (l + 1e-16f);
    int fb = fl * 4;
    float o[4];
#pragma unroll
    for (int i = 0; i < 4; i++) {
      int j = fb + i;
      float ov = acc[i] * li + b2v[j];
      ov = (ov - m[j]) * rsqrtf(v[j] + 1e-5f) * g[j] + bb[j];
      o[i] = fmaxf(ov, 0.f);
    }
    *(float4*)(out_emb + node * OUTD + fb) = make_float4(o[0], o[1], o[2], o[3]);
  }
}

// ---------- classifier + regressor heads (thread per node) ----------
__global__ __launch_bounds__(256) void k_mlp(
    const float* __restrict__ embf,
    const float* __restrict__ cw1, const float* __restrict__ cb1,
    const float* __restrict__ cw2, const float* __restrict__ cb2,
    const float* __restrict__ rw1, const float* __restrict__ rb1,
    const float* __restrict__ rw2, const float* __restrict__ rb2,
    float* __restrict__ out_roles, float* __restrict__ out_energy) {
  __shared__ float C1[OUTD * HID2D], R1[OUTD * HID2D];
  __shared__ float C2[HID2D * 3], CB1[HID2D], RB1[HID2D], R2[HID2D];
  __shared__ float CB2v[3], RB2v;
  int t = threadIdx.x;
  for (int i = t; i < OUTD * HID2D; i += 256) { C1[i] = cw1[i]; R1[i] = rw1[i]; }
  if (t < HID2D) { CB1[t] = cb1[t]; RB1[t] = rb1[t]; R2[t] = rw2[t]; }
  if (t < HID2D * 3) C2[t] = cw2[t];
  if (t < 3) CB2v[t] = cb2[t];
  if (t == 0) RB2v = rb2[0];
  __syncthreads();
  int node = blockIdx.x * 256 + t;
  if (node >= NN) return;
  float e[OUTD];
#pragma unroll
  for (int k = 0; k < OUTD; k++) e[k] = embf[node * OUTD + k];
  float r0 = CB2v[0], r1 = CB2v[1], r2 = CB2v[2], en = RB2v;
  for (int j = 0; j < HID2D; j++) {
    float hc = CB1[j], hr = RB1[j];
#pragma unroll
    for (int k = 0; k < OUTD; k++) {
      hc += e[k] * C1[k * HID2D + j];
      hr += e[k] * R1[k * HID2D + j];
    }
    hc = fmaxf(hc, 0.f);
    hr = fmaxf(hr, 0.f);
    r0 += hc * C2[j * 3 + 0];
    r1 += hc * C2[j * 3 + 1];
    r2 += hc * C2[j * 3 + 2];
    en += hr * R2[j];
  }
  out_roles[node * 3 + 0] = r0;
  out_roles[node * 3 + 1] = r1;
  out_roles[node * 3 + 2] = r2;
  out_energy[node] = en;
}

extern "C" void kernel_launch(void* const* d_in, const int* in_sizes, int n_in,
                              void* d_out, int out_size, void* d_ws, size_t ws_size,
                              hipStream_t stream) {
  const float* x    = (const float*)d_in[0];
  const int*   ei   = (const int*)d_in[1];
  const float* W1   = (const float*)d_in[2];
  const float* as1w = (const float*)d_in[3];
  const float* ad1w = (const float*)d_in[4];
  const float* b1   = (const float*)d_in[5];
  const float* W2   = (const float*)d_in[6];
  const float* as2w = (const float*)d_in[7];
  const float* ad2w = (const float*)d_in[8];
  const float* b2v  = (const float*)d_in[9];
  const float* bn1g = (const float*)d_in[10];
  const float* bn1b = (const float*)d_in[11];
  const float* bn1m = (const float*)d_in[12];
  const float* bn1v = (const float*)d_in[13];
  const float* bn2g = (const float*)d_in[14];
  const float* bn2b = (const float*)d_in[15];
  const float* bn2m = (const float*)d_in[16];
  const float* bn2v = (const float*)d_in[17];
  const float* cw1  = (const float*)d_in[18];
  const float* cb1  = (const float*)d_in[19];
  const float* cw2  = (const float*)d_in[20];
  const float* cb2  = (const float*)d_in[21];
  const float* rw1  = (const float*)d_in[22];
  const float* rb1  = (const float*)d_in[23];
  const float* rw2  = (const float*)d_in[24];
  const float* rb2  = (const float*)d_in[25];

  // workspace (~49 MB); bins aliases hbn; h2u aliases h1u
  uint*  h1u = (uint*)d_ws;               // N*32 uints (bf16x2) = 12.8MB
  float* hbn = (float*)(h1u + NN * 32);   // N*64 f32 = 25.6MB
  float* as1 = hbn + NN * HIDD;           // N*4
  float* ad1 = as1 + NN * NHEADS;         // N*4
  int* rowp  = (int*)(ad1 + NN * NHEADS); // N+1
  int* srcs  = rowp + NN + 1;             // ETOT
  int* bcur  = srcs + ETOT;               // 256
  int* gbase = bcur + 256;                // 256
  int* bins  = (int*)hbn;                 // NBUCK*CAP = 2.0M ints (8MB < 25.6MB)
  uint* h2u  = h1u;                       // N*16 uints fits h1u slot
  float* as2 = as1;
  float* ad2 = ad1;

  float* out        = (float*)d_out;
  float* out_emb    = out;                   // N*32
  float* out_roles  = out + NN * OUTD;       // N*3
  float* out_energy = out + NN * (OUTD + 3); // N*1

  hipMemsetAsync(bcur, 0, NBUCK * sizeof(int), stream);
  k_bin<<<(ETOT + EPB - 1) / EPB, 256, 0, stream>>>(ei, bcur, bins);
  k_scanb<<<1, 256, 0, stream>>>(bcur, gbase, rowp);
  k_csr<<<NBUCK, 256, 0, stream>>>(bcur, gbase, bins, rowp, srcs);
  k_lin1<<<NN / 8, 256, 0, stream>>>(x, W1, as1w, ad1w, h1u, as1, ad1);
  k_agg1<<<NN / 4, 256, 0, stream>>>(rowp, srcs, h1u, as1, ad1, b1, bn1g, bn1b, bn1m, bn1v, hbn);
  k_lin2<<<NN / 16, 256, 0, stream>>>(hbn, W2, as2w, ad2w, h2u, as2, ad2);
  k_agg2<<<NN / 4, 256, 0, stream>>>(rowp, srcs, h2u, as2, ad2, b2v, bn2g, bn2b, bn2m, bn2v, out_emb);
  k_mlp<<<(NN + 255) / 256, 256, 0, stream>>>(out_emb, cw1, cb1, cw2, cb2, rw1, rb1, rw2, rb2, out_roles, out_energy);
}